// Round 10
// baseline (124.032 us; speedup 1.0000x reference)
//
#include <hip/hip_runtime.h>

#define KSZ   121
#define KMEAN 60
#define IMW   512
#define IMH   512
#define NPLANES 24   // 8 * 3

typedef float    f32x4 __attribute__((ext_vector_type(4)));
typedef float    f32x2 __attribute__((ext_vector_type(2)));
typedef int      i32x4 __attribute__((ext_vector_type(4)));
typedef unsigned u32x4 __attribute__((ext_vector_type(4)));
typedef __fp16   f16x2 __attribute__((ext_vector_type(2)));   // builtin-compatible

// CK-style raw buffer intrinsics: HW bounds check returns 0 for OOB lanes.
__device__ f32x4 buf_load_x4(i32x4 srsrc, int voffset, int soffset, int aux)
    __asm("llvm.amdgcn.raw.buffer.load.v4f32");
__device__ unsigned buf_load_u32(i32x4 srsrc, int voffset, int soffset, int aux)
    __asm("llvm.amdgcn.raw.buffer.load.i32");
__device__ void buf_store_f32(float data, i32x4 srsrc, int voffset, int soffset, int aux)
    __asm("llvm.amdgcn.raw.buffer.store.f32");

// NOTE: SRD lives in SGPRs -> every input to make_srd MUST be wave-uniform.
// hblur invariant: rows handled by a wave must be wave-uniform (one SRD/row).
__device__ __forceinline__ i32x4 make_srd(const void* p, int bytes) {
    union { const void* p; unsigned u[2]; } a; a.p = p;
    i32x4 r;
    r.x = (int)__builtin_amdgcn_readfirstlane((int)a.u[0]);   // wave-uniform base
    r.y = (int)__builtin_amdgcn_readfirstlane((int)a.u[1]);
    r.z = bytes;          // num_records: OOB load -> 0, OOB store -> dropped
    r.w = 0x00020000;     // raw dword SRD word3 (gfx9/gfx950)
    return r;
}

// Clamp a possibly-wrapped-negative byte offset to a positive OOB value.
__device__ __forceinline__ int safev(int voff) {
    unsigned u = (unsigned)voff;
    return (int)(u < 0x7fff0000u ? u : 0x7fff0000u);   // one v_min_u32
}

union HU { unsigned u; f16x2 h; };

// ---------------------------------------------------------------------------
// Kernel 1: weight tables.
//  fp32 (hblur):  ws[0..123] taps w-hat (121..123=0); Lh[512] @128; Rh[512] @640.
//  fp16 (vblur):  taps hq = fp16(w-hat / S2) renormalized so sum(hq) ~= 1;
//    WPe[64] dwords @1152: (hq[2j],hq[2j+1]);  WPo[64] @1216: (hq[2j-1],hq[2j]);
//    Lv[512] @1280, Rv[512] @1792 — prefix tables built FROM hq so the
//    zero-pad + edge-correction identity is exact for the quantized kernel.
//  tmp (fp16 pair-packed) at byte offset 9216.
// ---------------------------------------------------------------------------
__global__ __launch_bounds__(128) void weights_kernel(const float* __restrict__ sigma,
                                                      float* __restrict__ ws) {
    __shared__ float w[124];     // fp32 normalized taps
    __shared__ float P[121];     // fp32 prefix
    __shared__ float hqf[124];   // fp16-quantized taps (as fp32 values)
    __shared__ float Pv[121];    // prefix of quantized taps
    int t = threadIdx.x;
    float s = sigma[0] * 8.0f + 16.0f;
    float ninv = -1.0f / (2.0f * s * s);
    if (t < 121) { float d = (float)(t - KMEAN); w[t] = __expf(d * d * ninv); }
    if (t >= 121 && t < 124) w[t] = 0.f;
    __syncthreads();
    if (t == 0) {
        float sum = 0.f;
        for (int i = 0; i < 121; ++i) sum += w[i];
        float inv = 1.f / sum, run = 0.f;
        for (int i = 0; i < 121; ++i) { float wi = w[i] * inv; w[i] = wi; run += wi; P[i] = run; }
        // fp16 quantize + one renormalization iteration
        float S2 = 0.f;
        for (int i = 0; i < 121; ++i) S2 += (float)(__fp16)w[i];
        float i2 = 1.f / S2, run2 = 0.f;
        for (int i = 0; i < 121; ++i) {
            float q = (float)(__fp16)(w[i] * i2);
            hqf[i] = q; run2 += q; Pv[i] = run2;
        }
        hqf[121] = 0.f; hqf[122] = 0.f; hqf[123] = 0.f;
    }
    __syncthreads();
    ws[t] = w[t < 124 ? t : 0] * (t < 124 ? 1.f : 0.f);   // taps 0..123, rest 0
    if (t < 61) {   // packed fp16 pair tables (pad to 64 dwords each)
        HU e, o;
        e.h.x = (__fp16)hqf[2*t];
        e.h.y = (__fp16)hqf[2*t + 1];
        o.h.x = (__fp16)((t == 0) ? 0.f : hqf[2*t - 1]);
        o.h.y = (__fp16)hqf[2*t];
        ((unsigned*)ws)[1152 + t] = e.u;
        ((unsigned*)ws)[1216 + t] = o.u;
    } else if (t < 64) {
        ((unsigned*)ws)[1152 + t] = 0u;
        ((unsigned*)ws)[1216 + t] = 0u;
    }
    float Sf = Pv[120];
    #pragma unroll
    for (int j = 0; j < 4; ++j) {
        int o = t * 4 + j;
        ws[128  + o] = (o <= 59)  ? P[59 - o]           : 0.f;   // Lh
        ws[640  + o] = (o >= 452) ? (1.f - P[571 - o])  : 0.f;   // Rh
        ws[1280 + o] = (o <= 59)  ? Pv[59 - o]          : 0.f;   // Lv
        ws[1792 + o] = (o >= 452) ? (Sf - Pv[571 - o])  : 0.f;   // Rv
    }
}

// ---------------------------------------------------------------------------
// Kernel 2: horizontal pass — proven r5/r8 body, now TWO rows per wave via
// two wave-uniform SRDs (rows 2p, 2p+1), sharing the scalar weight loads.
// Epilogue packs (rowA, rowB) per col into fp16 pair-dwords with ONE
// v_cvt_pkrtz each -> tmp layout dword[pair][col]. 64 thr/row-pair,
// 8 outputs/thread/row; per tap-quad: 2 buffer_load_dwordx4 + 64 FMA.
// ---------------------------------------------------------------------------
__global__ __launch_bounds__(256) void hblur(const float* __restrict__ x,
                                             const float* __restrict__ ws,
                                             unsigned* __restrict__ tmpw) {
    const int tid  = threadIdx.x;
    const int t    = tid & 63;                      // output group: cols 8t..8t+7
    const int pair = blockIdx.x * 4 + (tid >> 6);   // row pair (rows 2p, 2p+1)

    const float* __restrict__ xr0 = x + (size_t)(2 * pair) * IMW;
    const float* __restrict__ xr1 = xr0 + IMW;
    const i32x4 srd0 = make_srd(xr0, IMW * 4);
    const i32x4 srd1 = make_srd(xr1, IMW * 4);
    const f32x4* __restrict__ w4 = (const f32x4*)ws;

    const int voff = 32 * t - 240;                  // byte offset of quad (2t-15)

    float a0=0.f,a1=0.f,a2=0.f,a3=0.f,a4=0.f,a5=0.f,a6=0.f,a7=0.f;
    float b0=0.f,b1=0.f,b2=0.f,b3=0.f,b4=0.f,b5=0.f,b6=0.f,b7=0.f;
    f32x4 A0 = buf_load_x4(srd0, safev(voff),      0, 0);
    f32x4 A1 = buf_load_x4(srd0, safev(voff + 16), 0, 0);
    f32x4 B0 = buf_load_x4(srd1, safev(voff),      0, 0);
    f32x4 B1 = buf_load_x4(srd1, safev(voff + 16), 0, 0);
    #pragma unroll
    for (int c = 0; c < 31; ++c) {                  // taps 4c..4c+3 (121..123 w=0)
        f32x4 A2 = buf_load_x4(srd0, safev(voff + 32 + 16 * c), 0, 0);
        f32x4 B2 = buf_load_x4(srd1, safev(voff + 32 + 16 * c), 0, 0);
        f32x4 w  = w4[c];                           // uniform -> s_load_dwordx4
        a0 += w.x*A0.x + w.y*A0.y + w.z*A0.z + w.w*A0.w;
        a1 += w.x*A0.y + w.y*A0.z + w.z*A0.w + w.w*A1.x;
        a2 += w.x*A0.z + w.y*A0.w + w.z*A1.x + w.w*A1.y;
        a3 += w.x*A0.w + w.y*A1.x + w.z*A1.y + w.w*A1.z;
        a4 += w.x*A1.x + w.y*A1.y + w.z*A1.z + w.w*A1.w;
        a5 += w.x*A1.y + w.y*A1.z + w.z*A1.w + w.w*A2.x;
        a6 += w.x*A1.z + w.y*A1.w + w.z*A2.x + w.w*A2.y;
        a7 += w.x*A1.w + w.y*A2.x + w.z*A2.y + w.w*A2.z;
        b0 += w.x*B0.x + w.y*B0.y + w.z*B0.z + w.w*B0.w;
        b1 += w.x*B0.y + w.y*B0.z + w.z*B0.w + w.w*B1.x;
        b2 += w.x*B0.z + w.y*B0.w + w.z*B1.x + w.w*B1.y;
        b3 += w.x*B0.w + w.y*B1.x + w.z*B1.y + w.w*B1.z;
        b4 += w.x*B1.x + w.y*B1.y + w.z*B1.z + w.w*B1.w;
        b5 += w.x*B1.y + w.y*B1.z + w.z*B1.w + w.w*B2.x;
        b6 += w.x*B1.z + w.y*B1.w + w.z*B2.x + w.w*B2.y;
        b7 += w.x*B1.w + w.y*B2.x + w.z*B2.y + w.w*B2.z;
        A0 = A1; A1 = A2; B0 = B1; B1 = B2;
    }

    // replicate-pad corrections (per row), then pack (rowA, rowB) fp16 pairs
    const float x0a = xr0[0], xNa = xr0[IMW - 1];
    const float x0b = xr1[0], xNb = xr1[IMW - 1];
    const f32x4* __restrict__ L4 = (const f32x4*)(ws + 128);
    const f32x4* __restrict__ R4 = (const f32x4*)(ws + 640);
    f32x4 La = L4[2*t], Lb = L4[2*t+1], Ra = R4[2*t], Rb = R4[2*t+1];
    a0 += x0a*La.x + xNa*Ra.x;  a1 += x0a*La.y + xNa*Ra.y;
    a2 += x0a*La.z + xNa*Ra.z;  a3 += x0a*La.w + xNa*Ra.w;
    a4 += x0a*Lb.x + xNa*Rb.x;  a5 += x0a*Lb.y + xNa*Rb.y;
    a6 += x0a*Lb.z + xNa*Rb.z;  a7 += x0a*Lb.w + xNa*Rb.w;
    b0 += x0b*La.x + xNb*Ra.x;  b1 += x0b*La.y + xNb*Ra.y;
    b2 += x0b*La.z + xNb*Ra.z;  b3 += x0b*La.w + xNb*Ra.w;
    b4 += x0b*Lb.x + xNb*Rb.x;  b5 += x0b*Lb.y + xNb*Rb.y;
    b6 += x0b*Lb.z + xNb*Rb.z;  b7 += x0b*Lb.w + xNb*Rb.w;

    HU p0,p1,p2,p3,p4,p5,p6,p7;
    p0.h = __builtin_amdgcn_cvt_pkrtz(a0, b0);   // lo = even row, hi = odd row
    p1.h = __builtin_amdgcn_cvt_pkrtz(a1, b1);
    p2.h = __builtin_amdgcn_cvt_pkrtz(a2, b2);
    p3.h = __builtin_amdgcn_cvt_pkrtz(a3, b3);
    p4.h = __builtin_amdgcn_cvt_pkrtz(a4, b4);
    p5.h = __builtin_amdgcn_cvt_pkrtz(a5, b5);
    p6.h = __builtin_amdgcn_cvt_pkrtz(a6, b6);
    p7.h = __builtin_amdgcn_cvt_pkrtz(a7, b7);
    u32x4 s0; s0.x=p0.u; s0.y=p1.u; s0.z=p2.u; s0.w=p3.u;
    u32x4 s1; s1.x=p4.u; s1.y=p5.u; s1.z=p6.u; s1.w=p7.u;
    u32x4* __restrict__ o4 = (u32x4*)(tmpw + (size_t)pair * IMW);
    o4[2*t]     = s0;
    o4[2*t + 1] = s1;
}

// ---------------------------------------------------------------------------
// Kernel 3: vertical pass via v_dot2_f32_f16. Thread = 1 col x 32 output
// rows. tmp dword m holds fp16 rows (2m, 2m+1) of the col -> each dot2 folds
// 2 taps: 61 dot2/output (vs 124 FMA). Pair window m-M0 = 0..75, 19 quad
// chunks with 2-chunk register prefetch. Weight pair for output i at chunk
// slot q: table parity i&1, index j = q - (i>>1), j in [0,60] (compile-time
// skip outside). SRD zero-fill handles rows <0/>511; replicate restored by
// Lv/Rv corrections built from the SAME quantized fp16 taps.
// ---------------------------------------------------------------------------
#define VR 32
__global__ __launch_bounds__(256) void vblur(const unsigned* __restrict__ tmpw,
                                             const float* __restrict__ ws,
                                             float* __restrict__ out) {
    const int t      = threadIdx.x;                // 0..255
    const int b      = blockIdx.x;                 // 0..767
    const int plane  = b >> 5;
    const int within = b & 31;
    const int c      = (within & 1) * 256 + t;     // column 0..511
    const int r0     = (within >> 1) * VR;         // output rows r0..r0+31 (even)
    const int M0     = (r0 - KMEAN) >> 1;          // first pair index (may be <0)
    const int voff   = c * 4;

    const unsigned* __restrict__ tp = tmpw + (size_t)plane * (IMW * IMH / 2);
    float* __restrict__ op = out + (size_t)plane * (IMW * IMH);
    const i32x4 srdT = make_srd(tp, IMW * IMH * 2);   // fp16 plane: 512 KB
    const i32x4 srdO = make_srd(op, IMW * IMH * 4);
    const unsigned* __restrict__ wpe = (const unsigned*)ws + 1152;
    const unsigned* __restrict__ wpo = (const unsigned*)ws + 1216;

    // pair-chunk prefetch pipeline: D = chunk q4, P0 = q4+1, P1 = q4+2
    unsigned D[4], P0[4], P1[4];
    #pragma unroll
    for (int e = 0; e < 4; ++e) D[e]  = buf_load_u32(srdT, voff, (M0 + e)     * (IMW * 4), 0);
    #pragma unroll
    for (int e = 0; e < 4; ++e) P0[e] = buf_load_u32(srdT, voff, (M0 + 4 + e) * (IMW * 4), 0);
    #pragma unroll
    for (int e = 0; e < 4; ++e) P1[e] = buf_load_u32(srdT, voff, (M0 + 8 + e) * (IMW * 4), 0);

    float acc[VR];
    #pragma unroll
    for (int i = 0; i < VR; ++i) acc[i] = 0.f;

    #pragma unroll
    for (int c4 = 0; c4 < 19; ++c4) {              // pair slots q = 4*c4..4*c4+3
        #pragma unroll
        for (int s = 0; s < 4; ++s) {
            const int q = 4 * c4 + s;
            if (q > 75) continue;                  // window is 76 pair-rows
            HU d; d.u = D[s];
            #pragma unroll
            for (int i = 0; i < VR; ++i) {
                const int j = q - (i >> 1);
                if (j >= 0 && j <= 60) {
                    HU wp; wp.u = (i & 1) ? wpo[j] : wpe[j];   // uniform s_load
                    acc[i] = __builtin_amdgcn_fdot2(wp.h, d.h, acc[i], false);
                }
            }
        }
        if (c4 < 18) {
            #pragma unroll
            for (int e = 0; e < 4; ++e) D[e] = P0[e];
            #pragma unroll
            for (int e = 0; e < 4; ++e) P0[e] = P1[e];
            if (c4 < 17) {
                #pragma unroll
                for (int e = 0; e < 4; ++e)
                    P1[e] = buf_load_u32(srdT, voff, (M0 + 4*c4 + 12 + e) * (IMW * 4), 0);
            }
        }
    }

    // replicate-pad corrections: row 0 = lo(pair 0), row 511 = hi(pair 255)
    HU t0; t0.u = buf_load_u32(srdT, voff, 0, 0);
    HU tn; tn.u = buf_load_u32(srdT, voff, (IMH / 2 - 1) * (IMW * 4), 0);
    const float T0 = (float)t0.h.x;
    const float TN = (float)tn.h.y;
    const float* __restrict__ Lv = ws + 1280;
    const float* __restrict__ Rv = ws + 1792;
    #pragma unroll
    for (int i = 0; i < VR; ++i) {
        float L = Lv[r0 + i], R = Rv[r0 + i];      // uniform -> s_load
        acc[i] += L * T0 + R * TN;
    }

    #pragma unroll
    for (int i = 0; i < VR; ++i)
        buf_store_f32(acc[i], srdO, voff, (r0 + i) * (IMW * 4), 0);
}

// ---------------------------------------------------------------------------
extern "C" void kernel_launch(void* const* d_in, const int* in_sizes, int n_in,
                              void* d_out, int out_size, void* d_ws, size_t ws_size,
                              hipStream_t stream) {
    const float* x     = (const float*)d_in[0];
    const float* sigma = (const float*)d_in[1];
    float* out = (float*)d_out;

    // ws floats: [0,128) taps fp32 | [128,640) Lh | [640,1152) Rh |
    //            [1152,1280) WPe/WPo dwords | [1280,1792) Lv | [1792,2304) Rv
    // fp16 pair-packed tmp at byte 9216.
    float* ws_f = (float*)d_ws;
    unsigned* tmpw = (unsigned*)((char*)d_ws + 9216);

    weights_kernel<<<1, 128, 0, stream>>>(sigma, ws_f);
    hblur<<<NPLANES * IMH / 8, 256, 0, stream>>>(x, ws_f, tmpw);
    vblur<<<NPLANES * (IMH / VR) * 2, 256, 0, stream>>>(tmpw, ws_f, out);
}